// Round 13
// baseline (540.738 us; speedup 1.0000x reference)
//
#include <hip/hip_runtime.h>

#define NT 512              // 8 waves per block
#define NWAVE 8
#define NTS 256             // helper kernels
#define CAP 2064            // rank-pair sums are 2047/2048; 2-pass fallback if bigger
#define SLOT 5              // ceil(CAP/NT)
#define GMAXN 1536          // max single group size
#define TVITERS 20
#define BISECT 14
#define BMAX 4096
#define NBIN 1025           // size bins: sizes-512 in [0,1024]

__device__ int g_off[BMAX];
__device__ int g_rank[BMAX];
__device__ int g_maxdeg;

// K1: exclusive scan of sizes -> g_off; counting-sort by size -> g_rank.
__global__ __launch_bounds__(NTS) void k_scan(const int* __restrict__ sizes, int B) {
  __shared__ int wt[4];
  __shared__ int histC[NBIN];
  __shared__ int histO[NBIN];
  int t = threadIdx.x;
  int lane = t & 63, wid = t >> 6;

  int per = (B + NTS - 1) / NTS;
  int base = t * per;
  int acc = 0;
  for (int k = 0; k < per; ++k) {
    int i = base + k;
    if (i < B) acc += sizes[i];
  }
  int inc = acc;
  #pragma unroll
  for (int o = 1; o < 64; o <<= 1) {
    int n = __shfl_up(inc, o, 64);
    if (lane >= o) inc += n;
  }
  if (lane == 63) wt[wid] = inc;
  __syncthreads();
  int wpre = 0;
  #pragma unroll
  for (int w = 0; w < 4; ++w) wpre += (w < wid) ? wt[w] : 0;
  int run = wpre + inc - acc;
  for (int k = 0; k < per; ++k) {
    int i = base + k;
    if (i < B) { g_off[i] = run; run += sizes[i]; }
  }
  if (t == 0) g_maxdeg = 0;

  for (int i = t; i < NBIN; i += NTS) histC[i] = 0;
  __syncthreads();
  for (int i = t; i < B; i += NTS) atomicAdd(&histC[sizes[i] - 512], 1);
  __syncthreads();
  int c[5];
  int tot = 0;
  #pragma unroll
  for (int k = 0; k < 5; ++k) {
    int i = t * 5 + k;
    int v = (i < NBIN) ? histC[i] : 0;
    c[k] = tot; tot += v;
  }
  inc = tot;
  #pragma unroll
  for (int o = 1; o < 64; o <<= 1) {
    int n = __shfl_up(inc, o, 64);
    if (lane >= o) inc += n;
  }
  if (lane == 63) wt[wid] = inc;
  __syncthreads();
  wpre = 0;
  #pragma unroll
  for (int w = 0; w < 4; ++w) wpre += (w < wid) ? wt[w] : 0;
  int basep = wpre + (inc - tot);
  #pragma unroll
  for (int k = 0; k < 5; ++k) {
    int i = t * 5 + k;
    if (i < NBIN) histO[i] = basep + c[k];
  }
  __syncthreads();
  for (int i = t; i < B; i += NTS) {
    int r = atomicAdd(&histO[sizes[i] - 512], 1);
    g_rank[r] = i;
  }
}

// K2: per-group max degree -> global atomicMax. Chain part analytic.
__global__ __launch_bounds__(NTS) void k_deg(const int* __restrict__ sizes,
                                             const int* __restrict__ edges,
                                             int N, int B) {
  __shared__ int cnt[GMAXN];
  __shared__ int wred[4];
  int g = blockIdx.x;
  int t = threadIdx.x;
  int s = sizes[g];
  int off = g_off[g];
  for (int i = t; i < s; i += NTS)
    cnt[i] = 2 - (i == 0 ? 1 : 0) - (i == s - 1 ? 1 : 0);
  __syncthreads();
  const int2* re2 = (const int2*)(edges) + (N - B) + off;
  for (int j = t; j < s; j += NTS) {
    int2 e = re2[j];
    atomicAdd(&cnt[e.x - off], 1);
    atomicAdd(&cnt[e.y - off], 1);
  }
  __syncthreads();
  int m = 0;
  for (int i = t; i < s; i += NTS) m = max(m, cnt[i]);
  #pragma unroll
  for (int o = 32; o > 0; o >>= 1) m = max(m, __shfl_down(m, o, 64));
  if ((t & 63) == 0) wred[t >> 6] = m;
  __syncthreads();
  if (t == 0) {
    m = max(max(wred[0], wred[1]), max(wred[2], wred[3]));
    atomicMax(&g_maxdeg, m);
  }
}

// K3: one 512-thread block per RANK-PAIR, STRIDED ownership (conflict-free
// structured accesses). NO CSR: phase B is LDS float atomicAdd into a
// double-buffered y. Chain edges ride registers + shfl; wave boundaries use
// one exec-masked atomic. ~5 LDS ops/node/iter (was ~10), 2 barriers/iter.
__global__ __launch_bounds__(NT)
void k_main(const float* __restrict__ x,
            const int* __restrict__ sizes,
            const int* __restrict__ edges,
            float* __restrict__ out,
            int N, int B) {
  __shared__ float yA[CAP];
  __shared__ float yB[CAP];
  __shared__ float redf[2][2 * NWAVE];

  int b = blockIdx.x;
  int t = threadIdx.x;
  int lane = t & 63, wid = t >> 6;
  int g1 = g_rank[b];
  int g2i = B - 1 - b;
  int g2 = (g2i != b) ? g_rank[g2i] : -1;
  int s1g = sizes[g1], off1g = g_off[g1];
  int s2g = 0, off2g = 0;
  if (g2 >= 0) { s2g = sizes[g2]; off2g = g_off[g2]; }
  float step = 1.0f / (2.0f * (float)g_maxdeg);
  int nch = N - B;                      // base row of random edges
  int npass = (s1g + s2g <= CAP) ? 1 : 2;

  for (int pass = 0; pass < npass; ++pass) {
    int ss1, oo1, ss2, oo2;
    if (npass == 1) { ss1 = s1g; oo1 = off1g; ss2 = s2g; oo2 = off2g; }
    else { ss1 = pass ? s2g : s1g; oo1 = pass ? off2g : off1g; ss2 = 0; oo2 = 0; }
    int S = ss1 + ss2;
    __syncthreads();

    // ---- random edges -> regs (strided, endpoints local, packed a|b<<16)
    uint ab[SLOT];
    #pragma unroll
    for (int k = 0; k < SLOT; ++k) {
      int j = t + k * NT;
      uint pk = 0;
      if (j < S) {
        int2 e;
        if (j < ss1) { e = ((const int2*)edges)[nch + oo1 + j];
                       pk = (uint)(e.x - oo1) | ((uint)(e.y - oo1) << 16); }
        else         { e = ((const int2*)edges)[nch + oo2 + (j - ss1)];
                       pk = (uint)(e.x - oo2 + ss1) | ((uint)(e.y - oo2 + ss1) << 16); }
      }
      ab[k] = pk;
    }
    // ---- x -> regs; init yA = x
    float xr[SLOT];
    #pragma unroll
    for (int k = 0; k < SLOT; ++k) {
      int i = t + k * NT;
      float v = 0.0f;
      if (i < S) v = (i < ss1) ? x[oo1 + i] : x[oo2 + i - ss1];
      xr[k] = v;
      if (i < S) yA[i] = v;
    }
    float uC[SLOT], uRr[SLOT];
    #pragma unroll
    for (int k = 0; k < SLOT; ++k) { uC[k] = 0.0f; uRr[k] = 0.0f; }
    __syncthreads();

    float* yIn = yA;
    float* yOut = yB;
    for (int it = 0; it < TVITERS; ++it) {
      // ---- Phase A: reads + register u updates + yOut init (x + chain)
      float yi[SLOT], ya[SLOT], yb[SLOT];
      #pragma unroll
      for (int k = 0; k < SLOT; ++k) {
        int i = t + k * NT;
        yi[k] = (i < S) ? yIn[i] : 0.0f;
      }
      #pragma unroll
      for (int k = 0; k < SLOT; ++k) {
        int j = t + k * NT;
        if (j < S) {
          ya[k] = yIn[ab[k] & 0xFFFFu];
          yb[k] = yIn[ab[k] >> 16];
        }
      }
      // chain-u updates: y[i+1] via shfl_down (lane63: masked LDS read)
      #pragma unroll
      for (int k = 0; k < SLOT; ++k) {
        int i = t + k * NT;
        float ynx = __shfl_down(yi[k], 1, 64);
        if (lane == 63 && i + 1 < S) ynx = yIn[i + 1];
        bool hasR = (i + 1 < S) && (i + 1 != ss1);
        if (hasR) {
          float nu = uC[k] + step * (yi[k] - ynx);
          uC[k] = fminf(1.0f, fmaxf(-1.0f, nu));
        }
      }
      // random-u updates
      #pragma unroll
      for (int k = 0; k < SLOT; ++k) {
        int j = t + k * NT;
        if (j < S) {
          float nu = uRr[k] + step * (ya[k] - yb[k]);
          uRr[k] = fminf(1.0f, fmaxf(-1.0f, nu));
        }
      }
      // init yOut = x + chain terms (left via shfl_up; lane0 gets it by atomic)
      #pragma unroll
      for (int k = 0; k < SLOT; ++k) {
        int i = t + k * NT;
        float upL = __shfl_up(uC[k], 1, 64);
        if (i < S) {
          float y = xr[k];
          if (lane > 0 && i > 0 && i != ss1) y += upL;
          if ((i + 1 < S) && (i + 1 != ss1)) y -= uC[k];
          yOut[i] = y;
        }
      }
      __syncthreads();
      // ---- Phase A2: atomic scatter of random-edge u + wave-boundary chain
      if (lane == 63) {
        #pragma unroll
        for (int k = 0; k < SLOT; ++k) {
          int i = t + k * NT;
          if ((i + 1 < S) && (i + 1 != ss1)) atomicAdd(&yOut[i + 1], uC[k]);
        }
      }
      #pragma unroll
      for (int k = 0; k < SLOT; ++k) {
        int j = t + k * NT;
        if (j < S) {
          atomicAdd(&yOut[ab[k] & 0xFFFFu], -uRr[k]);
          atomicAdd(&yOut[ab[k] >> 16], uRr[k]);
        }
      }
      __syncthreads();
      float* tmp = yIn; yIn = yOut; yOut = tmp;
    }

    // ---- read final y
    float yreg[SLOT];
    #pragma unroll
    for (int k = 0; k < SLOT; ++k) {
      int i = t + k * NT;
      yreg[k] = (i < S) ? yIn[i] : -1e30f;
    }

    // ---- segmented sparsemax (both groups simultaneously)
    float m1 = -1e30f, m2 = -1e30f;
    #pragma unroll
    for (int k = 0; k < SLOT; ++k) {
      int i = t + k * NT;
      if (i < S) { if (i < ss1) m1 = fmaxf(m1, yreg[k]); else m2 = fmaxf(m2, yreg[k]); }
    }
    #pragma unroll
    for (int o = 1; o < 64; o <<= 1) {
      m1 = fmaxf(m1, __shfl_xor(m1, o, 64));
      m2 = fmaxf(m2, __shfl_xor(m2, o, 64));
    }
    if (lane == 0) { redf[0][wid] = m1; redf[0][NWAVE + wid] = m2; }
    __syncthreads();
    m1 = -1e30f; m2 = -1e30f;
    #pragma unroll
    for (int w = 0; w < NWAVE; ++w) {
      m1 = fmaxf(m1, redf[0][w]);
      m2 = fmaxf(m2, redf[0][NWAVE + w]);
    }

    float lo1 = m1 - 1.0f, hi1 = m1, lo2 = m2 - 1.0f, hi2 = m2;
    int par = 1;
    for (int r = 0; r < BISECT; ++r) {
      float mid1 = 0.5f * (lo1 + hi1), mid2 = 0.5f * (lo2 + hi2);
      float f1 = 0.0f, f2 = 0.0f;
      #pragma unroll
      for (int k = 0; k < SLOT; ++k) {
        int i = t + k * NT;
        if (i < S) {
          if (i < ss1) f1 += fmaxf(yreg[k] - mid1, 0.0f);
          else         f2 += fmaxf(yreg[k] - mid2, 0.0f);
        }
      }
      #pragma unroll
      for (int o = 1; o < 64; o <<= 1) {
        f1 += __shfl_xor(f1, o, 64);
        f2 += __shfl_xor(f2, o, 64);
      }
      if (lane == 0) { redf[par][wid] = f1; redf[par][NWAVE + wid] = f2; }
      __syncthreads();
      f1 = 0.0f; f2 = 0.0f;
      #pragma unroll
      for (int w = 0; w < NWAVE; ++w) {
        f1 += redf[par][w];
        f2 += redf[par][NWAVE + w];
      }
      par ^= 1;
      if (f1 >= 1.0f) lo1 = mid1; else hi1 = mid1;
      if (f2 >= 1.0f) lo2 = mid2; else hi2 = mid2;
    }
    __syncthreads();   // protect redf reuse below
    // exact refinement on identified supports
    float cf1 = 0.0f, S1 = 0.0f, cf2 = 0.0f, S2 = 0.0f;
    #pragma unroll
    for (int k = 0; k < SLOT; ++k) {
      int i = t + k * NT;
      if (i < S) {
        if (i < ss1) { if (yreg[k] > lo1) { cf1 += 1.0f; S1 += yreg[k]; } }
        else         { if (yreg[k] > lo2) { cf2 += 1.0f; S2 += yreg[k]; } }
      }
    }
    #pragma unroll
    for (int o = 1; o < 64; o <<= 1) {
      cf1 += __shfl_xor(cf1, o, 64);
      S1  += __shfl_xor(S1,  o, 64);
      cf2 += __shfl_xor(cf2, o, 64);
      S2  += __shfl_xor(S2,  o, 64);
    }
    float* redflat = (float*)redf;
    if (lane == 0) {
      redflat[wid] = cf1; redflat[NWAVE + wid] = S1;
      redflat[2 * NWAVE + wid] = cf2; redflat[3 * NWAVE + wid] = S2;
    }
    __syncthreads();
    cf1 = 0.0f; S1 = 0.0f; cf2 = 0.0f; S2 = 0.0f;
    #pragma unroll
    for (int w = 0; w < NWAVE; ++w) {
      cf1 += redflat[w];
      S1  += redflat[NWAVE + w];
      cf2 += redflat[2 * NWAVE + w];
      S2  += redflat[3 * NWAVE + w];
    }
    float tau1 = (S1 - 1.0f) / cf1;
    float tau2 = (cf2 > 0.0f) ? (S2 - 1.0f) / cf2 : 0.0f;

    float sf1 = (float)ss1, sf2 = (float)ss2;
    #pragma unroll
    for (int k = 0; k < SLOT; ++k) {
      int i = t + k * NT;
      if (i < S) {
        bool in2 = (i >= ss1);
        float tau = in2 ? tau2 : tau1;
        float sf = in2 ? sf2 : sf1;
        int o = in2 ? (oo2 + i - ss1) : (oo1 + i);
        out[o] = fmaxf(yreg[k] - tau, 0.0f) * sf;
      }
    }
  }
}

extern "C" void kernel_launch(void* const* d_in, const int* in_sizes, int n_in,
                              void* d_out, int out_size, void* d_ws, size_t ws_size,
                              hipStream_t stream) {
  const float* x = (const float*)d_in[0];
  const int* sizes = (const int*)d_in[1];
  const int* edges = (const int*)d_in[2];
  float* out = (float*)d_out;
  int N = in_sizes[0];
  int B = in_sizes[1];
  (void)d_ws; (void)ws_size; (void)n_in; (void)out_size;

  k_scan<<<1, NTS, 0, stream>>>(sizes, B);
  k_deg<<<B, NTS, 0, stream>>>(sizes, edges, N, B);
  int nb = (B + 1) / 2;
  k_main<<<nb, NT, 0, stream>>>(x, sizes, edges, out, N, B);
}

// Round 15
// 171.493 us; speedup vs baseline: 3.1531x; 3.1531x over previous
//
#include <hip/hip_runtime.h>

#define NT 512              // 8 waves per block (k_main)
#define NWAVE 8
#define NTP 256             // k_pre threads
#define CAP 2064            // rank-pair sums <=2049; 2-pass fallback if bigger
#define SLOT 5              // ceil(CAP/NT)
#define GMAXN 1536          // max single group size
#define TVITERS 20
#define BISECT 14
#define BMAX 4096
#define NBIN 1025           // size bins: sizes-512 in [0,1024]

__device__ int g_off[BMAX];
__device__ int g_rank[BMAX];
__device__ int g_degmax[BMAX];

// K1 (k_pre): every block g -> self-computed offset, degree max (CSR counts +
// analytic chain). Block 0 also counting-sorts groups by size -> g_rank.
// No global accumulators: all outputs are plain per-slot stores (replay-safe).
__global__ __launch_bounds__(NTP) void k_pre(const int* __restrict__ sizes,
                                             const int* __restrict__ edges,
                                             int N, int B) {
  __shared__ int cnt[GMAXN];     // degree counts; block0 reuses as histC
  __shared__ int histO[NBIN];
  __shared__ int red[4];
  int g = blockIdx.x;
  int t = threadIdx.x;
  int lane = t & 63, wid = t >> 6;

  // ---- offset = sum sizes[0..g)
  int acc = 0;
  for (int i = t; i < g; i += NTP) acc += sizes[i];
  #pragma unroll
  for (int o = 1; o < 64; o <<= 1) acc += __shfl_xor(acc, o, 64);
  if (lane == 0) red[wid] = acc;
  __syncthreads();
  int off = (red[0] + red[1]) + (red[2] + red[3]);
  int s = sizes[g];
  if (t == 0) g_off[g] = off;
  __syncthreads();

  // ---- degree count (random incidences) + analytic chain
  for (int i = t; i < s; i += NTP) cnt[i] = 0;
  __syncthreads();
  const int2* re2 = (const int2*)edges + (N - B) + off;
  for (int j = t; j < s; j += NTP) {
    int2 e = re2[j];
    atomicAdd(&cnt[e.x - off], 1);
    atomicAdd(&cnt[e.y - off], 1);
  }
  __syncthreads();
  int m = 0;
  for (int i = t; i < s; i += NTP) {
    int chain = 2 - (i == 0 ? 1 : 0) - (i == s - 1 ? 1 : 0);
    m = max(m, cnt[i] + chain);
  }
  #pragma unroll
  for (int o = 1; o < 64; o <<= 1) m = max(m, __shfl_xor(m, o, 64));
  if (lane == 0) red[wid] = m;
  __syncthreads();
  if (t == 0) {
    m = max(max(red[0], red[1]), max(red[2], red[3]));
    g_degmax[g] = m;
  }

  // ---- block 0: counting sort by size -> g_rank
  if (g == 0) {
    int* histC = cnt;            // reuse (NBIN <= GMAXN)
    __syncthreads();
    for (int i = t; i < NBIN; i += NTP) histC[i] = 0;
    __syncthreads();
    for (int i = t; i < B; i += NTP) atomicAdd(&histC[sizes[i] - 512], 1);
    __syncthreads();
    int c[5];
    int tot = 0;
    #pragma unroll
    for (int k = 0; k < 5; ++k) {
      int i = t * 5 + k;
      int v = (i < NBIN) ? histC[i] : 0;
      c[k] = tot; tot += v;
    }
    int inc = tot;
    #pragma unroll
    for (int o = 1; o < 64; o <<= 1) {
      int n = __shfl_up(inc, o, 64);
      if (lane >= o) inc += n;
    }
    __syncthreads();
    if (lane == 63) red[wid] = inc;
    __syncthreads();
    int wpre = 0;
    #pragma unroll
    for (int w = 0; w < 4; ++w) wpre += (w < wid) ? red[w] : 0;
    int basep = wpre + (inc - tot);
    #pragma unroll
    for (int k = 0; k < 5; ++k) {
      int i = t * 5 + k;
      if (i < NBIN) histO[i] = basep + c[k];
    }
    __syncthreads();
    for (int i = t; i < B; i += NTP) {
      int r = atomicAdd(&histO[sizes[i] - 512], 1);
      g_rank[r] = i;
    }
  }
}

// K2 (k_main): one 512-thread block per RANK-PAIR. Strided ownership
// (conflict-free structured LDS), pre-signed contiguous uE sum, chain edges
// fully in registers (shfl + uB wave-boundary array; no uCh). 29.3 KB LDS.
__global__ __launch_bounds__(NT)
void k_main(const float* __restrict__ x,
            const int* __restrict__ sizes,
            const int* __restrict__ edges,
            float* __restrict__ out,
            int N, int B) {
  __shared__ float yL[CAP];            // y (aliased as int cnt[] during build)
  __shared__ float uE[2 * CAP];        // pre-signed u entries (aliased as cur[])
  __shared__ ushort offL[CAP + 2];     // CSR offsets
  __shared__ float uB[NWAVE][SLOT];    // wave-boundary chain u
  __shared__ float redf[2][2 * NWAVE];
  __shared__ int wtot[NWAVE];
  __shared__ int mdred[NWAVE];

  int b = blockIdx.x;
  int t = threadIdx.x;
  int lane = t & 63, wid = t >> 6;

  // ---- global max degree from per-group maxima
  int md = 0;
  for (int i = t; i < B; i += NT) md = max(md, g_degmax[i]);
  #pragma unroll
  for (int o = 1; o < 64; o <<= 1) md = max(md, __shfl_xor(md, o, 64));
  if (lane == 0) mdred[wid] = md;
  __syncthreads();
  md = 0;
  #pragma unroll
  for (int w = 0; w < NWAVE; ++w) md = max(md, mdred[w]);
  float step = 1.0f / (2.0f * (float)md);

  int g1 = g_rank[b];
  int g2i = B - 1 - b;
  int g2 = (g2i != b) ? g_rank[g2i] : -1;
  int s1g = sizes[g1], off1g = g_off[g1];
  int s2g = 0, off2g = 0;
  if (g2 >= 0) { s2g = sizes[g2]; off2g = g_off[g2]; }
  int nch = N - B;                      // base row of random edges
  int npass = (s1g + s2g <= CAP) ? 1 : 2;

  for (int pass = 0; pass < npass; ++pass) {
    int ss1, oo1, ss2, oo2;
    if (npass == 1) { ss1 = s1g; oo1 = off1g; ss2 = s2g; oo2 = off2g; }
    else { ss1 = pass ? s2g : s1g; oo1 = pass ? off2g : off1g; ss2 = 0; oo2 = 0; }
    int S = ss1 + ss2;
    __syncthreads();

    // ---- random edges -> regs (strided, endpoints local, packed a|b<<16)
    uint ab[SLOT];
    #pragma unroll
    for (int k = 0; k < SLOT; ++k) {
      int j = t + k * NT;
      uint pk = 0;
      if (j < S) {
        int2 e;
        if (j < ss1) { e = ((const int2*)edges)[nch + oo1 + j];
                       pk = (uint)(e.x - oo1) | ((uint)(e.y - oo1) << 16); }
        else         { e = ((const int2*)edges)[nch + oo2 + (j - ss1)];
                       pk = (uint)(e.x - oo2 + ss1) | ((uint)(e.y - oo2 + ss1) << 16); }
      }
      ab[k] = pk;
    }
    // ---- x -> regs
    float xr[SLOT];
    #pragma unroll
    for (int k = 0; k < SLOT; ++k) {
      int i = t + k * NT;
      float v = 0.0f;
      if (i < S) v = (i < ss1) ? x[oo1 + i] : x[oo2 + i - ss1];
      xr[k] = v;
    }

    // ---- CSR build over union (random incidences only)
    int* cnt = (int*)yL;
    #pragma unroll
    for (int k = 0; k < SLOT; ++k) { int i = t + k * NT; if (i < S) cnt[i] = 0; }
    __syncthreads();
    #pragma unroll
    for (int k = 0; k < SLOT; ++k) {
      int j = t + k * NT;
      if (j < S) {
        atomicAdd(&cnt[ab[k] & 0xFFFFu], 1);
        atomicAdd(&cnt[ab[k] >> 16], 1);
      }
    }
    __syncthreads();
    // chunked exclusive scan: thread t owns [t*SLOT, t*SLOT+SLOT)
    int c[SLOT];
    int tot = 0;
    #pragma unroll
    for (int k = 0; k < SLOT; ++k) {
      int i = t * SLOT + k;
      int v = (i < S) ? cnt[i] : 0;
      c[k] = tot; tot += v;
    }
    int inc = tot;
    #pragma unroll
    for (int o = 1; o < 64; o <<= 1) {
      int n = __shfl_up(inc, o, 64);
      if (lane >= o) inc += n;
    }
    if (lane == 63) wtot[wid] = inc;
    __syncthreads();
    int wpre = 0;
    #pragma unroll
    for (int w = 0; w < NWAVE; ++w) wpre += (w < wid) ? wtot[w] : 0;
    int basep = wpre + (inc - tot);
    int* cur = (int*)uE;
    #pragma unroll
    for (int k = 0; k < SLOT; ++k) {
      int i = t * SLOT + k;
      if (i < S) { int v = basep + c[k]; offL[i] = (ushort)v; cur[i] = v; }
    }
    if (t == 0) offL[S] = (ushort)(2 * S);
    __syncthreads();
    // fill: record this edge's two entry positions into regs
    uint pw[SLOT];
    #pragma unroll
    for (int k = 0; k < SLOT; ++k) {
      int j = t + k * NT;
      uint v = 0;
      if (j < S) {
        int pa = atomicAdd(&cur[ab[k] & 0xFFFFu], 1);
        int pb = atomicAdd(&cur[ab[k] >> 16], 1);
        v = (uint)pa | ((uint)pb << 16);
      }
      pw[k] = v;
    }
    // hoist CSR ranges (reads offL only; concurrent with fill is safe)
    uint pq[SLOT];
    #pragma unroll
    for (int k = 0; k < SLOT; ++k) {
      int i = t + k * NT;
      uint v = 0;
      if (i < S) { uint p0 = offL[i]; uint n = (uint)offL[i + 1] - p0; v = p0 | (n << 16); }
      pq[k] = v;
    }
    // init y = x (cnt dead), u = 0
    float yreg[SLOT], uC[SLOT], uRr[SLOT];
    #pragma unroll
    for (int k = 0; k < SLOT; ++k) {
      int i = t + k * NT;
      uC[k] = 0.0f; uRr[k] = 0.0f;
      if (i < S) yL[i] = xr[k];
      yreg[k] = (i < S) ? xr[k] : -1e30f;
    }
    __syncthreads();

    // ---- TV iterations: 2 barriers each, chain via regs/shfl (no uCh)
    for (int it = 0; it < TVITERS; ++it) {
      bool last = (it == TVITERS - 1);
      // Phase A: batched random gathers + register chain updates
      float ya[SLOT], yb[SLOT];
      #pragma unroll
      for (int k = 0; k < SLOT; ++k) {
        int j = t + k * NT;
        if (j < S) {
          ya[k] = yL[ab[k] & 0xFFFFu];
          yb[k] = yL[ab[k] >> 16];
        }
      }
      #pragma unroll
      for (int k = 0; k < SLOT; ++k) {
        int i = t + k * NT;
        float ynx = __shfl_down(yreg[k], 1, 64);
        if (lane == 63 && i + 1 < S) ynx = yL[i + 1];
        if ((i + 1 < S) && (i + 1 != ss1)) {
          float nu = uC[k] + step * (yreg[k] - ynx);
          uC[k] = fminf(1.0f, fmaxf(-1.0f, nu));
        }
      }
      if (lane == 63) {
        #pragma unroll
        for (int k = 0; k < SLOT; ++k) uB[wid][k] = uC[k];
      }
      #pragma unroll
      for (int k = 0; k < SLOT; ++k) {
        int j = t + k * NT;
        if (j < S) {
          float nu = uRr[k] + step * (ya[k] - yb[k]);
          nu = fminf(1.0f, fmaxf(-1.0f, nu));
          uRr[k] = nu;
          uE[pw[k] & 0xFFFFu] = -nu;
          uE[pw[k] >> 16] = nu;
        }
      }
      __syncthreads();
      // Phase B: y = x + chain (shfl/uB) + contiguous pre-signed entry sum
      #pragma unroll
      for (int k = 0; k < SLOT; ++k) {
        float upL = __shfl_up(uC[k], 1, 64);
        if (lane == 0)
          upL = (wid > 0) ? uB[wid - 1][k] : ((k > 0) ? uB[NWAVE - 1][k - 1] : 0.0f);
        int i = t + k * NT;
        if (i < S) {
          float y = xr[k];
          if (i > 0 && i != ss1) y += upL;
          if ((i + 1 < S) && (i + 1 != ss1)) y -= uC[k];
          uint p = pq[k] & 0xFFFFu, n = pq[k] >> 16;
          for (uint q = 0; q < n; ++q) y += uE[p + q];
          yreg[k] = y;
          if (!last) yL[i] = y;
        }
      }
      if (!last) __syncthreads();
    }

    // ---- segmented sparsemax (both groups simultaneously)
    float m1 = -1e30f, m2 = -1e30f;
    #pragma unroll
    for (int k = 0; k < SLOT; ++k) {
      int i = t + k * NT;
      if (i < S) { if (i < ss1) m1 = fmaxf(m1, yreg[k]); else m2 = fmaxf(m2, yreg[k]); }
    }
    #pragma unroll
    for (int o = 1; o < 64; o <<= 1) {
      m1 = fmaxf(m1, __shfl_xor(m1, o, 64));
      m2 = fmaxf(m2, __shfl_xor(m2, o, 64));
    }
    if (lane == 0) { redf[0][wid] = m1; redf[0][NWAVE + wid] = m2; }
    __syncthreads();
    m1 = -1e30f; m2 = -1e30f;
    #pragma unroll
    for (int w = 0; w < NWAVE; ++w) {
      m1 = fmaxf(m1, redf[0][w]);
      m2 = fmaxf(m2, redf[0][NWAVE + w]);
    }

    float lo1 = m1 - 1.0f, hi1 = m1, lo2 = m2 - 1.0f, hi2 = m2;
    int par = 1;
    for (int r = 0; r < BISECT; ++r) {
      float mid1 = 0.5f * (lo1 + hi1), mid2 = 0.5f * (lo2 + hi2);
      float f1 = 0.0f, f2 = 0.0f;
      #pragma unroll
      for (int k = 0; k < SLOT; ++k) {
        int i = t + k * NT;
        if (i < S) {
          if (i < ss1) f1 += fmaxf(yreg[k] - mid1, 0.0f);
          else         f2 += fmaxf(yreg[k] - mid2, 0.0f);
        }
      }
      #pragma unroll
      for (int o = 1; o < 64; o <<= 1) {
        f1 += __shfl_xor(f1, o, 64);
        f2 += __shfl_xor(f2, o, 64);
      }
      if (lane == 0) { redf[par][wid] = f1; redf[par][NWAVE + wid] = f2; }
      __syncthreads();
      f1 = 0.0f; f2 = 0.0f;
      #pragma unroll
      for (int w = 0; w < NWAVE; ++w) {
        f1 += redf[par][w];
        f2 += redf[par][NWAVE + w];
      }
      par ^= 1;
      if (f1 >= 1.0f) lo1 = mid1; else hi1 = mid1;
      if (f2 >= 1.0f) lo2 = mid2; else hi2 = mid2;
    }
    __syncthreads();   // protect redf reuse below
    // exact refinement on identified supports
    float cf1 = 0.0f, S1 = 0.0f, cf2 = 0.0f, S2 = 0.0f;
    #pragma unroll
    for (int k = 0; k < SLOT; ++k) {
      int i = t + k * NT;
      if (i < S) {
        if (i < ss1) { if (yreg[k] > lo1) { cf1 += 1.0f; S1 += yreg[k]; } }
        else         { if (yreg[k] > lo2) { cf2 += 1.0f; S2 += yreg[k]; } }
      }
    }
    #pragma unroll
    for (int o = 1; o < 64; o <<= 1) {
      cf1 += __shfl_xor(cf1, o, 64);
      S1  += __shfl_xor(S1,  o, 64);
      cf2 += __shfl_xor(cf2, o, 64);
      S2  += __shfl_xor(S2,  o, 64);
    }
    float* redflat = (float*)redf;
    if (lane == 0) {
      redflat[wid] = cf1; redflat[NWAVE + wid] = S1;
      redflat[2 * NWAVE + wid] = cf2; redflat[3 * NWAVE + wid] = S2;
    }
    __syncthreads();
    cf1 = 0.0f; S1 = 0.0f; cf2 = 0.0f; S2 = 0.0f;
    #pragma unroll
    for (int w = 0; w < NWAVE; ++w) {
      cf1 += redflat[w];
      S1  += redflat[NWAVE + w];
      cf2 += redflat[2 * NWAVE + w];
      S2  += redflat[3 * NWAVE + w];
    }
    float tau1 = (S1 - 1.0f) / cf1;
    float tau2 = (cf2 > 0.0f) ? (S2 - 1.0f) / cf2 : 0.0f;

    float sf1 = (float)ss1, sf2 = (float)ss2;
    #pragma unroll
    for (int k = 0; k < SLOT; ++k) {
      int i = t + k * NT;
      if (i < S) {
        bool in2 = (i >= ss1);
        float tau = in2 ? tau2 : tau1;
        float sf = in2 ? sf2 : sf1;
        int o = in2 ? (oo2 + i - ss1) : (oo1 + i);
        out[o] = fmaxf(yreg[k] - tau, 0.0f) * sf;
      }
    }
  }
}

extern "C" void kernel_launch(void* const* d_in, const int* in_sizes, int n_in,
                              void* d_out, int out_size, void* d_ws, size_t ws_size,
                              hipStream_t stream) {
  const float* x = (const float*)d_in[0];
  const int* sizes = (const int*)d_in[1];
  const int* edges = (const int*)d_in[2];
  float* out = (float*)d_out;
  int N = in_sizes[0];
  int B = in_sizes[1];
  (void)d_ws; (void)ws_size; (void)n_in; (void)out_size;

  k_pre<<<B, NTP, 0, stream>>>(sizes, edges, N, B);
  int nb = (B + 1) / 2;
  k_main<<<nb, NT, 0, stream>>>(x, sizes, edges, out, N, B);
}

// Round 16
// 154.302 us; speedup vs baseline: 3.5044x; 1.1114x over previous
//
#include <hip/hip_runtime.h>

#define NT 512              // 8 waves per block (k_main)
#define NWAVE 8
#define NTP 256             // k_pre threads
#define CAP 2064            // rank-pair sums <=2049; 2-pass fallback if bigger
#define SLOT 5              // ceil(CAP/NT)
#define GMAXN 1536          // max single group size
#define TVITERS 20
#define BISECT 14
#define BMAX 4096
#define NBIN 1025           // size bins: sizes-512 in [0,1024]

__device__ int g_off[BMAX];
__device__ int g_rank[BMAX];
__device__ int g_degmax[BMAX];

// K1 (k_pre): every block g -> self-computed offset, degree max (CSR counts +
// analytic chain). Block 0 also counting-sorts groups by size -> g_rank.
__global__ __launch_bounds__(NTP) void k_pre(const int* __restrict__ sizes,
                                             const int* __restrict__ edges,
                                             int N, int B) {
  __shared__ int cnt[GMAXN];     // degree counts; block0 reuses as histC
  __shared__ int histO[NBIN];
  __shared__ int red[4];
  int g = blockIdx.x;
  int t = threadIdx.x;
  int lane = t & 63, wid = t >> 6;

  // ---- offset = sum sizes[0..g)
  int acc = 0;
  for (int i = t; i < g; i += NTP) acc += sizes[i];
  #pragma unroll
  for (int o = 1; o < 64; o <<= 1) acc += __shfl_xor(acc, o, 64);
  if (lane == 0) red[wid] = acc;
  __syncthreads();
  int off = (red[0] + red[1]) + (red[2] + red[3]);
  int s = sizes[g];
  if (t == 0) g_off[g] = off;
  __syncthreads();

  // ---- degree count (random incidences) + analytic chain
  for (int i = t; i < s; i += NTP) cnt[i] = 0;
  __syncthreads();
  const int2* re2 = (const int2*)edges + (N - B) + off;
  for (int j = t; j < s; j += NTP) {
    int2 e = re2[j];
    atomicAdd(&cnt[e.x - off], 1);
    atomicAdd(&cnt[e.y - off], 1);
  }
  __syncthreads();
  int m = 0;
  for (int i = t; i < s; i += NTP) {
    int chain = 2 - (i == 0 ? 1 : 0) - (i == s - 1 ? 1 : 0);
    m = max(m, cnt[i] + chain);
  }
  #pragma unroll
  for (int o = 1; o < 64; o <<= 1) m = max(m, __shfl_xor(m, o, 64));
  if (lane == 0) red[wid] = m;
  __syncthreads();
  if (t == 0) {
    m = max(max(red[0], red[1]), max(red[2], red[3]));
    g_degmax[g] = m;
  }

  // ---- block 0: counting sort by size -> g_rank
  if (g == 0) {
    int* histC = cnt;            // reuse (NBIN <= GMAXN)
    __syncthreads();
    for (int i = t; i < NBIN; i += NTP) histC[i] = 0;
    __syncthreads();
    for (int i = t; i < B; i += NTP) atomicAdd(&histC[sizes[i] - 512], 1);
    __syncthreads();
    int c[5];
    int tot = 0;
    #pragma unroll
    for (int k = 0; k < 5; ++k) {
      int i = t * 5 + k;
      int v = (i < NBIN) ? histC[i] : 0;
      c[k] = tot; tot += v;
    }
    int inc = tot;
    #pragma unroll
    for (int o = 1; o < 64; o <<= 1) {
      int n = __shfl_up(inc, o, 64);
      if (lane >= o) inc += n;
    }
    __syncthreads();
    if (lane == 63) red[wid] = inc;
    __syncthreads();
    int wpre = 0;
    #pragma unroll
    for (int w = 0; w < 4; ++w) wpre += (w < wid) ? red[w] : 0;
    int basep = wpre + (inc - tot);
    #pragma unroll
    for (int k = 0; k < 5; ++k) {
      int i = t * 5 + k;
      if (i < NBIN) histO[i] = basep + c[k];
    }
    __syncthreads();
    for (int i = t; i < B; i += NTP) {
      int r = atomicAdd(&histO[sizes[i] - 512], 1);
      g_rank[r] = i;
    }
  }
}

// K2 (k_main): one 512-thread block per RANK-PAIR — uniform work. R11 body:
// strided ownership, batched yn/ya/yb gathers (MLP), uCh LDS chain array,
// pre-signed contiguous uE sum, 2 barriers/iter. md reduced from g_degmax.
__global__ __launch_bounds__(NT)
void k_main(const float* __restrict__ x,
            const int* __restrict__ sizes,
            const int* __restrict__ edges,
            float* __restrict__ out,
            int N, int B) {
  __shared__ float yL[CAP];            // y (aliased as int cnt[] during build)
  __shared__ float uE[2 * CAP];        // pre-signed u entries (aliased as cur[])
  __shared__ float uCh[CAP];           // chain-edge u
  __shared__ ushort offL[CAP + 2];     // CSR offsets
  __shared__ float redf[2][2 * NWAVE];
  __shared__ int wtot[NWAVE];
  __shared__ int mdred[NWAVE];

  int b = blockIdx.x;
  int t = threadIdx.x;
  int lane = t & 63, wid = t >> 6;

  // ---- global max degree from per-group maxima (8 KB, L2-resident)
  int md = 0;
  for (int i = t; i < B; i += NT) md = max(md, g_degmax[i]);
  #pragma unroll
  for (int o = 1; o < 64; o <<= 1) md = max(md, __shfl_xor(md, o, 64));
  if (lane == 0) mdred[wid] = md;
  __syncthreads();
  md = 0;
  #pragma unroll
  for (int w = 0; w < NWAVE; ++w) md = max(md, mdred[w]);
  float step = 1.0f / (2.0f * (float)md);

  int g1 = g_rank[b];
  int g2i = B - 1 - b;
  int g2 = (g2i != b) ? g_rank[g2i] : -1;
  int s1g = sizes[g1], off1g = g_off[g1];
  int s2g = 0, off2g = 0;
  if (g2 >= 0) { s2g = sizes[g2]; off2g = g_off[g2]; }
  int nch = N - B;                      // base row of random edges
  int npass = (s1g + s2g <= CAP) ? 1 : 2;

  for (int pass = 0; pass < npass; ++pass) {
    int ss1, oo1, ss2, oo2;
    if (npass == 1) { ss1 = s1g; oo1 = off1g; ss2 = s2g; oo2 = off2g; }
    else { ss1 = pass ? s2g : s1g; oo1 = pass ? off2g : off1g; ss2 = 0; oo2 = 0; }
    int S = ss1 + ss2;
    __syncthreads();

    // ---- random edges -> regs (strided, endpoints local, packed a|b<<16)
    uint ab[SLOT];
    #pragma unroll
    for (int k = 0; k < SLOT; ++k) {
      int j = t + k * NT;
      uint pk = 0;
      if (j < S) {
        int2 e;
        if (j < ss1) { e = ((const int2*)edges)[nch + oo1 + j];
                       pk = (uint)(e.x - oo1) | ((uint)(e.y - oo1) << 16); }
        else         { e = ((const int2*)edges)[nch + oo2 + (j - ss1)];
                       pk = (uint)(e.x - oo2 + ss1) | ((uint)(e.y - oo2 + ss1) << 16); }
      }
      ab[k] = pk;
    }
    // ---- x -> regs
    float xr[SLOT];
    #pragma unroll
    for (int k = 0; k < SLOT; ++k) {
      int i = t + k * NT;
      float v = 0.0f;
      if (i < S) v = (i < ss1) ? x[oo1 + i] : x[oo2 + i - ss1];
      xr[k] = v;
    }

    // ---- CSR build over union (random incidences only)
    int* cnt = (int*)yL;
    #pragma unroll
    for (int k = 0; k < SLOT; ++k) { int i = t + k * NT; if (i < S) cnt[i] = 0; }
    __syncthreads();
    #pragma unroll
    for (int k = 0; k < SLOT; ++k) {
      int j = t + k * NT;
      if (j < S) {
        atomicAdd(&cnt[ab[k] & 0xFFFFu], 1);
        atomicAdd(&cnt[ab[k] >> 16], 1);
      }
    }
    __syncthreads();
    // chunked exclusive scan: thread t owns [t*SLOT, t*SLOT+SLOT)
    int c[SLOT];
    int tot = 0;
    #pragma unroll
    for (int k = 0; k < SLOT; ++k) {
      int i = t * SLOT + k;
      int v = (i < S) ? cnt[i] : 0;
      c[k] = tot; tot += v;
    }
    int inc = tot;
    #pragma unroll
    for (int o = 1; o < 64; o <<= 1) {
      int n = __shfl_up(inc, o, 64);
      if (lane >= o) inc += n;
    }
    if (lane == 63) wtot[wid] = inc;
    __syncthreads();
    int wpre = 0;
    #pragma unroll
    for (int w = 0; w < NWAVE; ++w) wpre += (w < wid) ? wtot[w] : 0;
    int basep = wpre + (inc - tot);
    int* cur = (int*)uE;
    #pragma unroll
    for (int k = 0; k < SLOT; ++k) {
      int i = t * SLOT + k;
      if (i < S) { int v = basep + c[k]; offL[i] = (ushort)v; cur[i] = v; }
    }
    if (t == 0) offL[S] = (ushort)(2 * S);
    __syncthreads();
    // fill: record this edge's two entry positions into regs
    uint pw[SLOT];
    #pragma unroll
    for (int k = 0; k < SLOT; ++k) {
      int j = t + k * NT;
      uint v = 0;
      if (j < S) {
        int pa = atomicAdd(&cur[ab[k] & 0xFFFFu], 1);
        int pb = atomicAdd(&cur[ab[k] >> 16], 1);
        v = (uint)pa | ((uint)pb << 16);
      }
      pw[k] = v;
    }
    // hoist CSR ranges (reads offL only; concurrent with fill is safe)
    uint pq[SLOT];
    #pragma unroll
    for (int k = 0; k < SLOT; ++k) {
      int i = t + k * NT;
      uint v = 0;
      if (i < S) { uint p0 = offL[i]; uint n = (uint)offL[i + 1] - p0; v = p0 | (n << 16); }
      pq[k] = v;
    }
    // init y = x, uCh = 0 (yL aliases cnt: safe, cnt no longer read)
    float yreg[SLOT], uC[SLOT], uRr[SLOT];
    #pragma unroll
    for (int k = 0; k < SLOT; ++k) {
      int i = t + k * NT;
      uC[k] = 0.0f; uRr[k] = 0.0f;
      if (i < S) { yL[i] = xr[k]; uCh[i] = 0.0f; }
      yreg[k] = (i < S) ? xr[k] : -1e30f;
    }
    __syncthreads();

    // ---- TV iterations: 2 barriers each, no atomics (R11 body)
    for (int it = 0; it < TVITERS; ++it) {
      bool last = (it == TVITERS - 1);
      // Phase A: batched independent gathers (MLP), then u updates
      float yn[SLOT], ya[SLOT], yb[SLOT];
      #pragma unroll
      for (int k = 0; k < SLOT; ++k) {
        int i = t + k * NT;
        yn[k] = (i + 1 < S) ? yL[i + 1] : 0.0f;
      }
      #pragma unroll
      for (int k = 0; k < SLOT; ++k) {
        int j = t + k * NT;
        if (j < S) {
          ya[k] = yL[ab[k] & 0xFFFFu];
          yb[k] = yL[ab[k] >> 16];
        }
      }
      #pragma unroll
      for (int k = 0; k < SLOT; ++k) {
        int i = t + k * NT;
        bool ch = (i < S - 1) && (i != ss1 - 1);
        if (ch) {
          float nu = uC[k] + step * (yreg[k] - yn[k]);
          nu = fminf(1.0f, fmaxf(-1.0f, nu));
          uC[k] = nu;
          uCh[i] = nu;
        }
      }
      #pragma unroll
      for (int k = 0; k < SLOT; ++k) {
        int j = t + k * NT;
        if (j < S) {
          float nu = uRr[k] + step * (ya[k] - yb[k]);
          nu = fminf(1.0f, fmaxf(-1.0f, nu));
          uRr[k] = nu;
          uE[pw[k] & 0xFFFFu] = -nu;
          uE[pw[k] >> 16] = nu;
        }
      }
      __syncthreads();
      // Phase B: y = x + chain terms + contiguous pre-signed entry sum
      #pragma unroll
      for (int k = 0; k < SLOT; ++k) {
        int i = t + k * NT;
        if (i < S) {
          float y = xr[k];
          if (i > 0 && i != ss1) y += uCh[i - 1];
          if ((i < S - 1) && (i != ss1 - 1)) y -= uC[k];
          uint p = pq[k] & 0xFFFFu, n = pq[k] >> 16;
          for (uint q = 0; q < n; ++q) y += uE[p + q];
          yreg[k] = y;
          if (!last) yL[i] = y;
        }
      }
      if (!last) __syncthreads();
    }

    // ---- segmented sparsemax (both groups simultaneously)
    float m1 = -1e30f, m2 = -1e30f;
    #pragma unroll
    for (int k = 0; k < SLOT; ++k) {
      int i = t + k * NT;
      if (i < S) { if (i < ss1) m1 = fmaxf(m1, yreg[k]); else m2 = fmaxf(m2, yreg[k]); }
    }
    #pragma unroll
    for (int o = 1; o < 64; o <<= 1) {
      m1 = fmaxf(m1, __shfl_xor(m1, o, 64));
      m2 = fmaxf(m2, __shfl_xor(m2, o, 64));
    }
    if (lane == 0) { redf[0][wid] = m1; redf[0][NWAVE + wid] = m2; }
    __syncthreads();
    m1 = -1e30f; m2 = -1e30f;
    #pragma unroll
    for (int w = 0; w < NWAVE; ++w) {
      m1 = fmaxf(m1, redf[0][w]);
      m2 = fmaxf(m2, redf[0][NWAVE + w]);
    }

    float lo1 = m1 - 1.0f, hi1 = m1, lo2 = m2 - 1.0f, hi2 = m2;
    int par = 1;
    for (int r = 0; r < BISECT; ++r) {
      float mid1 = 0.5f * (lo1 + hi1), mid2 = 0.5f * (lo2 + hi2);
      float f1 = 0.0f, f2 = 0.0f;
      #pragma unroll
      for (int k = 0; k < SLOT; ++k) {
        int i = t + k * NT;
        if (i < S) {
          if (i < ss1) f1 += fmaxf(yreg[k] - mid1, 0.0f);
          else         f2 += fmaxf(yreg[k] - mid2, 0.0f);
        }
      }
      #pragma unroll
      for (int o = 1; o < 64; o <<= 1) {
        f1 += __shfl_xor(f1, o, 64);
        f2 += __shfl_xor(f2, o, 64);
      }
      if (lane == 0) { redf[par][wid] = f1; redf[par][NWAVE + wid] = f2; }
      __syncthreads();
      f1 = 0.0f; f2 = 0.0f;
      #pragma unroll
      for (int w = 0; w < NWAVE; ++w) {
        f1 += redf[par][w];
        f2 += redf[par][NWAVE + w];
      }
      par ^= 1;
      if (f1 >= 1.0f) lo1 = mid1; else hi1 = mid1;
      if (f2 >= 1.0f) lo2 = mid2; else hi2 = mid2;
    }
    __syncthreads();   // protect redf reuse below
    // exact refinement on identified supports
    float cf1 = 0.0f, S1 = 0.0f, cf2 = 0.0f, S2 = 0.0f;
    #pragma unroll
    for (int k = 0; k < SLOT; ++k) {
      int i = t + k * NT;
      if (i < S) {
        if (i < ss1) { if (yreg[k] > lo1) { cf1 += 1.0f; S1 += yreg[k]; } }
        else         { if (yreg[k] > lo2) { cf2 += 1.0f; S2 += yreg[k]; } }
      }
    }
    #pragma unroll
    for (int o = 1; o < 64; o <<= 1) {
      cf1 += __shfl_xor(cf1, o, 64);
      S1  += __shfl_xor(S1,  o, 64);
      cf2 += __shfl_xor(cf2, o, 64);
      S2  += __shfl_xor(S2,  o, 64);
    }
    float* redflat = (float*)redf;
    if (lane == 0) {
      redflat[wid] = cf1; redflat[NWAVE + wid] = S1;
      redflat[2 * NWAVE + wid] = cf2; redflat[3 * NWAVE + wid] = S2;
    }
    __syncthreads();
    cf1 = 0.0f; S1 = 0.0f; cf2 = 0.0f; S2 = 0.0f;
    #pragma unroll
    for (int w = 0; w < NWAVE; ++w) {
      cf1 += redflat[w];
      S1  += redflat[NWAVE + w];
      cf2 += redflat[2 * NWAVE + w];
      S2  += redflat[3 * NWAVE + w];
    }
    float tau1 = (S1 - 1.0f) / cf1;
    float tau2 = (cf2 > 0.0f) ? (S2 - 1.0f) / cf2 : 0.0f;

    float sf1 = (float)ss1, sf2 = (float)ss2;
    #pragma unroll
    for (int k = 0; k < SLOT; ++k) {
      int i = t + k * NT;
      if (i < S) {
        bool in2 = (i >= ss1);
        float tau = in2 ? tau2 : tau1;
        float sf = in2 ? sf2 : sf1;
        int o = in2 ? (oo2 + i - ss1) : (oo1 + i);
        out[o] = fmaxf(yreg[k] - tau, 0.0f) * sf;
      }
    }
  }
}

extern "C" void kernel_launch(void* const* d_in, const int* in_sizes, int n_in,
                              void* d_out, int out_size, void* d_ws, size_t ws_size,
                              hipStream_t stream) {
  const float* x = (const float*)d_in[0];
  const int* sizes = (const int*)d_in[1];
  const int* edges = (const int*)d_in[2];
  float* out = (float*)d_out;
  int N = in_sizes[0];
  int B = in_sizes[1];
  (void)d_ws; (void)ws_size; (void)n_in; (void)out_size;

  k_pre<<<B, NTP, 0, stream>>>(sizes, edges, N, B);
  int nb = (B + 1) / 2;
  k_main<<<nb, NT, 0, stream>>>(x, sizes, edges, out, N, B);
}